// Round 6
// baseline (1539.801 us; speedup 1.0000x reference)
//
#include <hip/hip_runtime.h>
#include <hip/hip_bf16.h>
#include <math.h>

// Problem constants (fixed by setup_inputs)
#define BB 128
#define DD 512
#define HH 1024
#define NB 32     // num_coeff_per_dim
#define MM 63     // 2N-1 simpson points
#define TT 16
#define ITERS 10

// ws layout (float units)
#define OFF_U       0        // 32 fp32
#define OFF_TTRUE   64       // 64 fp32 (tt[63]=0)
#define OFF_PHIOUT  128      // 512 fp32 [n][t]
#define OFF_PHIF_BF 1024     // bf16 [64 m][32 n]  (row 63 = 0)   = 1024 floats
#define OFF_QT_BF   2048     // bf16 [32 j][64 m]  (col 63 = 0)   = 1024 floats
#define HDRF        4096
#define OFF_BCT     HDRF                     // bf16 [128][32][512] = 1048576 f
#define OFF_W1T     (OFF_BCT + 1048576)      // bf16 [1024][512]    = 262144 f
#define OFF_W2T     (OFF_W1T + 262144)       // bf16 [512][1024]    = 262144 f
// end = 1576960 floats = 6.3 MB

typedef __attribute__((ext_vector_type(8))) short bf16x8;
typedef __attribute__((ext_vector_type(4))) float f32x4;
typedef unsigned short ush;

// LDS layout (ush units) for solve_kernel
#define LDS_G    0                    // 16 waves x [32 h][40 n]        = 20480
#define LDS_T    20480                // 16 waves x [32 h][40 m-half]   = 20480
#define LDS_P    40960                // [32 j][stride 1048]            = 33536
#define LDS_PO   74496                // 512 fp32                       = 1024 ush
#define LDS_TOT  75520                // 151040 B

static __device__ __forceinline__ ush f2bf(float f) {
    unsigned int x = __builtin_bit_cast(unsigned int, f);
    unsigned int r = x + 0x7FFFu + ((x >> 16) & 1u);   // RNE
    return (ush)(r >> 16);
}

static __device__ __forceinline__ void store4bf(ush* p,
                                                float v0, float v1, float v2, float v3) {
    unsigned int lo = (unsigned int)f2bf(v0) | ((unsigned int)f2bf(v1) << 16);
    unsigned int hi = (unsigned int)f2bf(v2) | ((unsigned int)f2bf(v3) << 16);
    uint2 u; u.x = lo; u.y = hi;
    *(uint2*)p = u;   // 8B-aligned by construction
}

static __device__ __forceinline__ float tanh_fast(float x) {
    float e = exp2f(x * 2.88539008177793f);   // 2*log2(e)
    return 1.0f - 2.0f / (e + 1.0f);
}

// ---------------------------------------------------------------------------
// Setup: t grids, Phi_f, Phi_inv (double GJ, tie-broken parallel pivot),
// Q = R@Phi_inv, u, Phi_out, bf16 tables phif_bf [m][n] and qt_bf [j][m]
// ---------------------------------------------------------------------------
__global__ void setup_kernel(const float* __restrict__ t_span,
                             float* __restrict__ ws) {
    __shared__ double tsim[MM];
    __shared__ double ttrue_d[MM];
    __shared__ double wid[31];
    __shared__ double phid[NB * MM];   // [n][m]
    __shared__ double aug[NB * 64];    // [Phi | I]
    __shared__ double mlt[NB];
    __shared__ double Rl[MM * NB];
    __shared__ double Qd[MM * NB];     // [m][j]

    const int t = threadIdx.x;  // 64 threads = 1 wave
    const double PI = 3.14159265358979323846;
    const double t0 = (double)t_span[0];
    const double t1 = (double)t_span[TT - 1];

    if (t < MM) {
        double v;
        if ((t & 1) == 0) {
            int j = t >> 1;
            v = -cos(PI * (double)j / (double)(NB - 1));
        } else {
            int i = t >> 1;
            double a = -cos(PI * (double)i / (double)(NB - 1));
            double b = -cos(PI * (double)(i + 1) / (double)(NB - 1));
            v = 0.5 * (a + b);
        }
        tsim[t] = v;
        ttrue_d[t] = t0 + 0.5 * (t1 - t0) * (v + 1.0);
    }
    __syncthreads();
    if (t < 31) wid[t] = (ttrue_d[2 * t + 2] - ttrue_d[2 * t]) / 6.0;
    if (t < MM) ws[OFF_TTRUE + t] = (float)ttrue_d[t];
    if (t == 63) ws[OFF_TTRUE + 63] = 0.0f;

    if (t < MM) {
        double x = tsim[t];
        double r0 = 1.0, r1 = x;
        phid[0 * MM + t] = r0;
        phid[1 * MM + t] = r1;
        for (int n = 2; n < NB; n++) {
            double r2 = 2.0 * x * r1 - r0;
            phid[n * MM + t] = r2;
            r0 = r1; r1 = r2;
        }
    }
    __syncthreads();

    // phif_bf [m 64][n 32], row 63 = 0
    {
        ush* pf = (ush*)(ws + OFF_PHIF_BF);
        for (int f = t; f < 64 * 32; f += 64) {
            int m = f >> 5, n = f & 31;
            pf[f] = f2bf(m < MM ? (float)phid[n * MM + m] : 0.0f);
        }
    }

    // augmented [Phi | I], Phi[r][c] = phid[r*MM + 2c]
    for (int f = t; f < NB * 64; f += 64) {
        int r = f >> 6, c = f & 63;
        double v;
        if (c < NB) v = phid[r * MM + 2 * c];
        else        v = ((c - NB) == r) ? 1.0 : 0.0;
        aug[f] = v;
    }
    __syncthreads();

    for (int k = 0; k < NB; k++) {
        // parallel argmax pivot with total-order tie-break (R3/R4 bug fix:
        // column 0 is (-1)^r -> exact 32-way tie; strict '>' left p non-uniform)
        int rr = t & 31;
        double cand = (rr >= k) ? fabs(aug[rr * 64 + k]) : -1.0;
        int idx = rr;
        #pragma unroll
        for (int off = 16; off >= 1; off >>= 1) {
            double ov = __shfl_xor(cand, off);
            int oi = __shfl_xor(idx, off);
            if (ov > cand || (ov == cand && oi < idx)) { cand = ov; idx = oi; }
        }
        int p = __shfl(idx, 0);
        __syncthreads();
        if (p != k) {
            double tmp = aug[k * 64 + t];
            aug[k * 64 + t] = aug[p * 64 + t];
            aug[p * 64 + t] = tmp;
        }
        __syncthreads();
        double pv = aug[k * 64 + k];
        __syncthreads();
        aug[k * 64 + t] *= (1.0 / pv);
        __syncthreads();
        if (t < NB) mlt[t] = aug[t * 64 + k];
        __syncthreads();
        for (int r = 0; r < NB; r++) {
            if (r != k) aug[r * 64 + t] -= mlt[r] * aug[k * 64 + t];
        }
        __syncthreads();
    }
    // Phi_inv[i][j] = aug[i*64 + 32 + j]

    if (t < MM) {
        double acc = 0.0;
        Rl[t * NB + 0] = 0.0;
        for (int i = 1; i < NB; i++) {
            int ip = i - 1;
            double w = 0.0;
            if (t == 2 * ip)     w += wid[ip];
            if (t == 2 * ip + 1) w += 4.0 * wid[ip];
            if (t == 2 * ip + 2) w += wid[ip];
            acc += w;
            Rl[t * NB + i] = acc;
        }
    }
    __syncthreads();

    // Qd = R @ Phi_inv  (63 x 32)
    for (int f = t; f < MM * NB; f += 64) {
        int m = f >> 5, j = f & 31;
        double s = 0.0;
        for (int i = 0; i < NB; i++) s += Rl[m * NB + i] * aug[i * 64 + 32 + j];
        Qd[f] = s;
    }
    __syncthreads();

    // qt_bf [j 32][m 64], col 63 = 0
    {
        ush* qt = (ush*)(ws + OFF_QT_BF);
        for (int f = t; f < 32 * 64; f += 64) {
            int j = f >> 6, m = f & 63;
            qt[f] = f2bf(m < MM ? (float)Qd[m * NB + j] : 0.0f);
        }
    }
    // u[j] = sum_i Phi_inv[i][j]
    if (t < NB) {
        double s = 0.0;
        for (int i = 0; i < NB; i++) s += aug[i * 64 + 32 + t];
        ws[OFF_U + t] = (float)s;
    }
    // Phi_out [n][t] (32 x 16)
    if (t < TT) {
        double x = -1.0 + 2.0 * ((double)t_span[t] - t0) / (t1 - t0);
        double r0 = 1.0, r1 = x;
        ws[OFF_PHIOUT + 0 * TT + t] = 1.0f;
        ws[OFF_PHIOUT + 1 * TT + t] = (float)x;
        for (int n = 2; n < NB; n++) {
            double r2 = 2.0 * x * r1 - r0;
            ws[OFF_PHIOUT + n * TT + t] = (float)r2;
            r0 = r1; r1 = r2;
        }
    }
}

// ---------------------------------------------------------------------------
// Transpose fp32 (R x C) -> bf16 (C x R)
// ---------------------------------------------------------------------------
__global__ __launch_bounds__(256) void transpose_f32_bf16(
        const float* __restrict__ in, ush* __restrict__ out, int R, int C) {
    __shared__ float tile[32][33];
    const int t = threadIdx.x;
    const int tc = blockIdx.x, tr = blockIdx.y;
    const int c = tc * 32 + (t & 31);
    #pragma unroll
    for (int i = 0; i < 4; i++) {
        int rl = (t >> 5) + i * 8;
        tile[rl][t & 31] = in[(size_t)(tr * 32 + rl) * C + c];
    }
    __syncthreads();
    #pragma unroll
    for (int i = 0; i < 4; i++) {
        int orl = (t >> 5) + i * 8;
        int orow = tc * 32 + orl;
        int ocol = tr * 32 + (t & 31);
        out[(size_t)orow * R + ocol] = f2bf(tile[t & 31][orl]);
    }
}

// B_init [b][d][n] fp32 -> Bct [b][n][d] bf16
__global__ __launch_bounds__(256) void binit_kernel(
        const float* __restrict__ Bi, ush* __restrict__ Bct) {
    __shared__ float tile[32][33];
    const int t = threadIdx.x;
    const int b = blockIdx.y, d0 = blockIdx.x * 32;
    #pragma unroll
    for (int i = 0; i < 4; i++) {
        int f = i * 256 + t;
        int dd = f >> 5, n = f & 31;
        tile[dd][n] = Bi[((size_t)b * DD + d0 + dd) * NB + n];
    }
    __syncthreads();
    #pragma unroll
    for (int i = 0; i < 4; i++) {
        int f = i * 256 + t;
        int n = f >> 5, dd = f & 31;
        Bct[((size_t)b * NB + n) * DD + d0 + dd] = f2bf(tile[dd][n]);
    }
}

// ---------------------------------------------------------------------------
// Persistent per-b solver: 128 blocks x 1024 threads (16 waves = 4/SIMD).
// Per iter: produce (each wave: 2 x 32-h chunks, G->Z->tanh->P into shared
// p_s) -> barrier -> consume (each wave: 32-d slice, K=1024, prefetched)
// -> epilogue -> barrier. 2 barriers/iter. Manual register double-buffer on
// all global loads in the K-loops.
// ---------------------------------------------------------------------------
__global__ __launch_bounds__(1024, 1) void solve_kernel(
        ush* __restrict__ Bct,            // [128][32][512] bf16, state
        const ush* __restrict__ W1t,      // [1024][512] bf16
        const ush* __restrict__ W2t,      // [512][1024] bf16
        const float* __restrict__ b1,     // [1024]
        const float* __restrict__ y_init, // [128][512]
        const float* __restrict__ ws,
        float* __restrict__ out)
{
    __shared__ __attribute__((aligned(16))) ush smem[LDS_TOT];
    ush* g_all = smem + LDS_G;
    ush* t_all = smem + LDS_T;
    ush* p_s   = smem + LDS_P;          // [32 j][stride 1048 ush]
    float* po_s = (float*)(smem + LDS_PO);

    const int tid  = threadIdx.x;
    const int w    = tid >> 6;          // 0..15
    const int lane = tid & 63;
    const int q    = lane >> 4;
    const int l15  = lane & 15;
    const int b    = blockIdx.x;
    const int dw   = w * 32;            // wave's d-slice for consume

    ush* gw = g_all + w * 1280;         // [32 h][40 n]
    ush* tw = t_all + w * 1280;         // [32 h][40 m-half]
    ush* bct = Bct + (size_t)b * (NB * DD);
    const ush* PF = (const ush*)(ws + OFF_PHIF_BF);
    const ush* QT = (const ush*)(ws + OFF_QT_BF);

    if (tid < 512) po_s[tid] = ws[OFF_PHIOUT + tid];

    // per-thread constants
    float yv[2];
    #pragma unroll
    for (int nt = 0; nt < 2; nt++)
        yv[nt] = y_init[(size_t)b * DD + dw + nt * 16 + l15];
    float4 uv[2], tt4[4];
    #pragma unroll
    for (int mt = 0; mt < 2; mt++) uv[mt] = *(const float4*)(ws + OFF_U + mt * 16 + q * 4);
    #pragma unroll
    for (int mt = 0; mt < 4; mt++) tt4[mt] = *(const float4*)(ws + OFF_TTRUE + mt * 16 + q * 4);
    __syncthreads();

    for (int it = 0; it < ITERS; it++) {
        // ================= produce: P[j][h] for this wave's 64 h =================
        for (int c = 0; c < 2; c++) {
            const int hb = w * 64 + c * 32;
            const ush* w1r0 = W1t + (size_t)(hb + l15) * DD + q * 8;
            const ush* w1r1 = W1t + (size_t)(hb + 16 + l15) * DD + q * 8;
            const ush* bcr0 = bct + (size_t)l15 * DD + q * 8;
            const ush* bcr1 = bct + (size_t)(16 + l15) * DD + q * 8;

            // ---- G = Bc^T W1 : M=32(n) N=32(h) K=512, 1-step reg prefetch ----
            f32x4 ag[2][2] = {};
            bf16x8 a0c = *(const bf16x8*)(bcr0);
            bf16x8 a1c = *(const bf16x8*)(bcr1);
            bf16x8 w0c = *(const bf16x8*)(w1r0);
            bf16x8 w1c = *(const bf16x8*)(w1r1);
            #pragma unroll
            for (int s = 0; s < 16; s++) {
                bf16x8 a0n, a1n, w0n, w1n;
                if (s < 15) {
                    int dn = (s + 1) * 32;
                    a0n = *(const bf16x8*)(bcr0 + dn);
                    a1n = *(const bf16x8*)(bcr1 + dn);
                    w0n = *(const bf16x8*)(w1r0 + dn);
                    w1n = *(const bf16x8*)(w1r1 + dn);
                }
                ag[0][0] = __builtin_amdgcn_mfma_f32_16x16x32_bf16(a0c, w0c, ag[0][0], 0, 0, 0);
                ag[0][1] = __builtin_amdgcn_mfma_f32_16x16x32_bf16(a0c, w1c, ag[0][1], 0, 0, 0);
                ag[1][0] = __builtin_amdgcn_mfma_f32_16x16x32_bf16(a1c, w0c, ag[1][0], 0, 0, 0);
                ag[1][1] = __builtin_amdgcn_mfma_f32_16x16x32_bf16(a1c, w1c, ag[1][1], 0, 0, 0);
                a0c = a0n; a1c = a1n; w0c = w0n; w1c = w1n;
            }
            // C-layout (row n=mt*16+q*4+r, col h=nt*16+l15) -> gw[h][n]
            #pragma unroll
            for (int mt = 0; mt < 2; mt++)
                #pragma unroll
                for (int nt = 0; nt < 2; nt++)
                    store4bf(gw + (nt * 16 + l15) * 40 + mt * 16 + q * 4,
                             ag[mt][nt][0], ag[mt][nt][1], ag[mt][nt][2], ag[mt][nt][3]);
            __builtin_amdgcn_s_waitcnt(0xc07f);  // lgkmcnt(0), wave-private RAW

            // ---- Z = Phi_f^T G : M=64(m) N=32(h) K=32(n) ----
            bf16x8 gb[2];
            #pragma unroll
            for (int nt = 0; nt < 2; nt++)
                gb[nt] = *(const bf16x8*)(gw + (nt * 16 + l15) * 40 + q * 8);
            f32x4 az[4][2] = {};
            #pragma unroll
            for (int mt = 0; mt < 4; mt++) {
                bf16x8 af = *(const bf16x8*)(PF + (mt * 16 + l15) * 32 + q * 8);
                az[mt][0] = __builtin_amdgcn_mfma_f32_16x16x32_bf16(af, gb[0], az[mt][0], 0, 0, 0);
                az[mt][1] = __builtin_amdgcn_mfma_f32_16x16x32_bf16(af, gb[1], az[mt][1], 0, 0, 0);
            }

            // ---- tanh + P = Q^T T, in two m-halves (tw holds 32 m) ----
            float b1v[2] = { b1[hb + l15], b1[hb + 16 + l15] };
            f32x4 ap[2][2] = {};
            #pragma unroll
            for (int half = 0; half < 2; half++) {
                #pragma unroll
                for (int mt2 = 0; mt2 < 2; mt2++) {
                    int mt = half * 2 + mt2;
                    #pragma unroll
                    for (int nt = 0; nt < 2; nt++) {
                        float v0 = tanh_fast(az[mt][nt][0] + tt4[mt].x * b1v[nt]);
                        float v1 = tanh_fast(az[mt][nt][1] + tt4[mt].y * b1v[nt]);
                        float v2 = tanh_fast(az[mt][nt][2] + tt4[mt].z * b1v[nt]);
                        float v3 = tanh_fast(az[mt][nt][3] + tt4[mt].w * b1v[nt]);
                        store4bf(tw + (nt * 16 + l15) * 40 + mt2 * 16 + q * 4, v0, v1, v2, v3);
                    }
                }
                __builtin_amdgcn_s_waitcnt(0xc07f);
                bf16x8 tb[2];
                #pragma unroll
                for (int nt = 0; nt < 2; nt++)
                    tb[nt] = *(const bf16x8*)(tw + (nt * 16 + l15) * 40 + q * 8);
                #pragma unroll
                for (int jt = 0; jt < 2; jt++) {
                    bf16x8 aq = *(const bf16x8*)(QT + (jt * 16 + l15) * 64 + half * 32 + q * 8);
                    ap[jt][0] = __builtin_amdgcn_mfma_f32_16x16x32_bf16(aq, tb[0], ap[jt][0], 0, 0, 0);
                    ap[jt][1] = __builtin_amdgcn_mfma_f32_16x16x32_bf16(aq, tb[1], ap[jt][1], 0, 0, 0);
                }
            }
            // store P chunk: p_s[j][hb + hl]  (C-layout row j, col h)
            #pragma unroll
            for (int jt = 0; jt < 2; jt++)
                #pragma unroll
                for (int nt = 0; nt < 2; nt++)
                    #pragma unroll
                    for (int r = 0; r < 4; r++)
                        p_s[(jt * 16 + q * 4 + r) * 1048 + hb + nt * 16 + l15] =
                            f2bf(ap[jt][nt][r]);
        }
        __syncthreads();   // p_s complete

        // ================= consume: Bn[j][dw..dw+32] = P W2 + y u =================
        f32x4 ack[2][2] = {};
        {
            const ush* w2r0 = W2t + (size_t)(dw + l15) * HH + q * 8;
            const ush* w2r1 = W2t + (size_t)(dw + 16 + l15) * HH + q * 8;
            bf16x8 wc0 = *(const bf16x8*)(w2r0);
            bf16x8 wc1 = *(const bf16x8*)(w2r1);
            #pragma unroll
            for (int s = 0; s < 32; s++) {
                bf16x8 wn0, wn1;
                if (s < 31) {
                    int hn = (s + 1) * 32;
                    wn0 = *(const bf16x8*)(w2r0 + hn);
                    wn1 = *(const bf16x8*)(w2r1 + hn);
                }
                bf16x8 pa0 = *(const bf16x8*)(p_s + l15 * 1048 + s * 32 + q * 8);
                bf16x8 pa1 = *(const bf16x8*)(p_s + (16 + l15) * 1048 + s * 32 + q * 8);
                ack[0][0] = __builtin_amdgcn_mfma_f32_16x16x32_bf16(pa0, wc0, ack[0][0], 0, 0, 0);
                ack[0][1] = __builtin_amdgcn_mfma_f32_16x16x32_bf16(pa0, wc1, ack[0][1], 0, 0, 0);
                ack[1][0] = __builtin_amdgcn_mfma_f32_16x16x32_bf16(pa1, wc0, ack[1][0], 0, 0, 0);
                ack[1][1] = __builtin_amdgcn_mfma_f32_16x16x32_bf16(pa1, wc1, ack[1][1], 0, 0, 0);
                wc0 = wn0; wc1 = wn1;
            }
        }

        // ================= epilogue =================
        if (it < ITERS - 1) {
            #pragma unroll
            for (int mt = 0; mt < 2; mt++) {
                #pragma unroll
                for (int nt = 0; nt < 2; nt++) {
                    #pragma unroll
                    for (int r = 0; r < 4; r++) {
                        float uvr = (r == 0) ? uv[mt].x : (r == 1) ? uv[mt].y
                                  : (r == 2) ? uv[mt].z : uv[mt].w;
                        float val = ack[mt][nt][r] + yv[nt] * uvr;
                        bct[(size_t)(mt * 16 + q * 4 + r) * DD + dw + nt * 16 + l15] = f2bf(val);
                    }
                }
            }
            __syncthreads();   // bct visible + p_s consumed before next iter
        } else {
            // all waves done reading p_s before o0 overlays it
            __syncthreads();
            float* out1 = out + (size_t)TT * BB * DD;
            float* o0 = (float*)(smem + LDS_P);   // 16 t x 512 d fp32 (32 KB)
            #pragma unroll
            for (int nt = 0; nt < 2; nt++) {
                int d = dw + nt * 16 + l15;
                float po_acc[TT];
                #pragma unroll
                for (int t16 = 0; t16 < TT; t16++) po_acc[t16] = 0.0f;
                #pragma unroll
                for (int mt = 0; mt < 2; mt++) {
                    #pragma unroll
                    for (int r = 0; r < 4; r++) {
                        int j = mt * 16 + q * 4 + r;
                        float uvr = (r == 0) ? uv[mt].x : (r == 1) ? uv[mt].y
                                  : (r == 2) ? uv[mt].z : uv[mt].w;
                        float val = ack[mt][nt][r] + yv[nt] * uvr;
                        out1[(size_t)b * (DD * NB) + (size_t)d * NB + j] = val;
                        #pragma unroll
                        for (int t16 = 0; t16 < TT; t16++)
                            po_acc[t16] += val * po_s[j * TT + t16];
                    }
                }
                #pragma unroll
                for (int t16 = 0; t16 < TT; t16++) {
                    po_acc[t16] += __shfl_xor(po_acc[t16], 16);
                    po_acc[t16] += __shfl_xor(po_acc[t16], 32);
                }
                if (q == 0) {
                    #pragma unroll
                    for (int t16 = 0; t16 < TT; t16++)
                        o0[t16 * DD + d] = po_acc[t16];
                }
            }
            __syncthreads();
            #pragma unroll
            for (int i = 0; i < 8; i++) {
                int f = i * 1024 + tid;          // t16 = f>>9, d = f&511
                out[(size_t)(f >> 9) * (BB * DD) + (size_t)b * DD + (f & 511)] = o0[f];
            }
        }
    }
}

// ---------------------------------------------------------------------------
extern "C" void kernel_launch(void* const* d_in, const int* in_sizes, int n_in,
                              void* d_out, int out_size, void* d_ws, size_t ws_size,
                              hipStream_t stream) {
    const float* t_span = (const float*)d_in[0];
    const float* y_init = (const float*)d_in[1];
    const float* B_init = (const float*)d_in[2];
    const float* W1     = (const float*)d_in[3];
    const float* b1     = (const float*)d_in[4];
    const float* W2     = (const float*)d_in[5];
    float* ws  = (float*)d_ws;
    float* out = (float*)d_out;

    ush* Bct = (ush*)(ws + OFF_BCT);
    ush* W1t = (ush*)(ws + OFF_W1T);
    ush* W2t = (ush*)(ws + OFF_W2T);

    setup_kernel<<<1, 64, 0, stream>>>(t_span, ws);
    transpose_f32_bf16<<<dim3(HH / 32, DD / 32), 256, 0, stream>>>(W1, W1t, DD, HH);
    transpose_f32_bf16<<<dim3(DD / 32, HH / 32), 256, 0, stream>>>(W2, W2t, HH, DD);
    binit_kernel<<<dim3(DD / 32, BB), 256, 0, stream>>>(B_init, Bct);

    solve_kernel<<<dim3(BB), 1024, 0, stream>>>(Bct, W1t, W2t, b1, y_init, ws, out);
}

// Round 7
// 1197.744 us; speedup vs baseline: 1.2856x; 1.2856x over previous
//
#include <hip/hip_runtime.h>
#include <hip/hip_bf16.h>
#include <math.h>

// Problem constants (fixed by setup_inputs)
#define BB 128
#define DD 512
#define HH 1024
#define NB 32     // num_coeff_per_dim
#define MM 63     // 2N-1 simpson points
#define TT 16
#define ITERS 10

// ws layout (float units)
#define OFF_U       0        // 32 fp32
#define OFF_TTRUE   64       // 64 fp32 (tt[63]=0)
#define OFF_PHIOUT  128      // 512 fp32 [n][t]
#define OFF_PHIF_BF 1024     // bf16 [64 m][32 n]  (row 63 = 0)   = 1024 floats
#define OFF_QT_BF   2048     // bf16 [32 j][64 m]  (col 63 = 0)   = 1024 floats
#define HDRF        4096
#define OFF_BCT     HDRF                     // bf16 [128][32][512] = 1048576 f
#define OFF_W1T     (OFF_BCT + 1048576)      // bf16 [1024][512]    = 262144 f
#define OFF_W2T     (OFF_W1T + 262144)       // bf16 [512][1024]    = 262144 f
// end = 1576960 floats = 6.3 MB

typedef __attribute__((ext_vector_type(8))) short bf16x8;
typedef __attribute__((ext_vector_type(4))) float f32x4;
typedef unsigned short ush;

// LDS layout (ush units) for solve_kernel
#define LDS_G    0                    // 16 waves x [32 h][40 n]        = 20480
#define LDS_T    20480                // 16 waves x [32 h][40 m-half]   = 20480
#define LDS_P    40960                // [32 j][stride 1048]            = 33536
#define LDS_PO   74496                // 512 fp32                       = 1024 ush
#define LDS_TOT  75520                // 151040 B

static __device__ __forceinline__ ush f2bf(float f) {
    unsigned int x = __builtin_bit_cast(unsigned int, f);
    unsigned int r = x + 0x7FFFu + ((x >> 16) & 1u);   // RNE
    return (ush)(r >> 16);
}

static __device__ __forceinline__ void store4bf(ush* p,
                                                float v0, float v1, float v2, float v3) {
    unsigned int lo = (unsigned int)f2bf(v0) | ((unsigned int)f2bf(v1) << 16);
    unsigned int hi = (unsigned int)f2bf(v2) | ((unsigned int)f2bf(v3) << 16);
    uint2 u; u.x = lo; u.y = hi;
    *(uint2*)p = u;   // 8B-aligned by construction
}

static __device__ __forceinline__ float tanh_fast(float x) {
    float e = exp2f(x * 2.88539008177793f);   // 2*log2(e)
    return 1.0f - 2.0f / (e + 1.0f);
}

// ---------------------------------------------------------------------------
// Setup: t grids, Phi_f, Phi_inv (double GJ, tie-broken parallel pivot),
// Q = R@Phi_inv, u, Phi_out, bf16 tables phif_bf [m][n] and qt_bf [j][m]
// ---------------------------------------------------------------------------
__global__ void setup_kernel(const float* __restrict__ t_span,
                             float* __restrict__ ws) {
    __shared__ double tsim[MM];
    __shared__ double ttrue_d[MM];
    __shared__ double wid[31];
    __shared__ double phid[NB * MM];   // [n][m]
    __shared__ double aug[NB * 64];    // [Phi | I]
    __shared__ double mlt[NB];
    __shared__ double Rl[MM * NB];
    __shared__ double Qd[MM * NB];     // [m][j]

    const int t = threadIdx.x;  // 64 threads = 1 wave
    const double PI = 3.14159265358979323846;
    const double t0 = (double)t_span[0];
    const double t1 = (double)t_span[TT - 1];

    if (t < MM) {
        double v;
        if ((t & 1) == 0) {
            int j = t >> 1;
            v = -cos(PI * (double)j / (double)(NB - 1));
        } else {
            int i = t >> 1;
            double a = -cos(PI * (double)i / (double)(NB - 1));
            double b = -cos(PI * (double)(i + 1) / (double)(NB - 1));
            v = 0.5 * (a + b);
        }
        tsim[t] = v;
        ttrue_d[t] = t0 + 0.5 * (t1 - t0) * (v + 1.0);
    }
    __syncthreads();
    if (t < 31) wid[t] = (ttrue_d[2 * t + 2] - ttrue_d[2 * t]) / 6.0;
    if (t < MM) ws[OFF_TTRUE + t] = (float)ttrue_d[t];
    if (t == 63) ws[OFF_TTRUE + 63] = 0.0f;

    if (t < MM) {
        double x = tsim[t];
        double r0 = 1.0, r1 = x;
        phid[0 * MM + t] = r0;
        phid[1 * MM + t] = r1;
        for (int n = 2; n < NB; n++) {
            double r2 = 2.0 * x * r1 - r0;
            phid[n * MM + t] = r2;
            r0 = r1; r1 = r2;
        }
    }
    __syncthreads();

    // phif_bf [m 64][n 32], row 63 = 0
    {
        ush* pf = (ush*)(ws + OFF_PHIF_BF);
        for (int f = t; f < 64 * 32; f += 64) {
            int m = f >> 5, n = f & 31;
            pf[f] = f2bf(m < MM ? (float)phid[n * MM + m] : 0.0f);
        }
    }

    // augmented [Phi | I], Phi[r][c] = phid[r*MM + 2c]
    for (int f = t; f < NB * 64; f += 64) {
        int r = f >> 6, c = f & 63;
        double v;
        if (c < NB) v = phid[r * MM + 2 * c];
        else        v = ((c - NB) == r) ? 1.0 : 0.0;
        aug[f] = v;
    }
    __syncthreads();

    for (int k = 0; k < NB; k++) {
        // parallel argmax pivot with total-order tie-break (R3/R4 bug fix:
        // column 0 is (-1)^r -> exact 32-way tie; strict '>' left p non-uniform)
        int rr = t & 31;
        double cand = (rr >= k) ? fabs(aug[rr * 64 + k]) : -1.0;
        int idx = rr;
        #pragma unroll
        for (int off = 16; off >= 1; off >>= 1) {
            double ov = __shfl_xor(cand, off);
            int oi = __shfl_xor(idx, off);
            if (ov > cand || (ov == cand && oi < idx)) { cand = ov; idx = oi; }
        }
        int p = __shfl(idx, 0);
        __syncthreads();
        if (p != k) {
            double tmp = aug[k * 64 + t];
            aug[k * 64 + t] = aug[p * 64 + t];
            aug[p * 64 + t] = tmp;
        }
        __syncthreads();
        double pv = aug[k * 64 + k];
        __syncthreads();
        aug[k * 64 + t] *= (1.0 / pv);
        __syncthreads();
        if (t < NB) mlt[t] = aug[t * 64 + k];
        __syncthreads();
        for (int r = 0; r < NB; r++) {
            if (r != k) aug[r * 64 + t] -= mlt[r] * aug[k * 64 + t];
        }
        __syncthreads();
    }
    // Phi_inv[i][j] = aug[i*64 + 32 + j]

    if (t < MM) {
        double acc = 0.0;
        Rl[t * NB + 0] = 0.0;
        for (int i = 1; i < NB; i++) {
            int ip = i - 1;
            double w = 0.0;
            if (t == 2 * ip)     w += wid[ip];
            if (t == 2 * ip + 1) w += 4.0 * wid[ip];
            if (t == 2 * ip + 2) w += wid[ip];
            acc += w;
            Rl[t * NB + i] = acc;
        }
    }
    __syncthreads();

    // Qd = R @ Phi_inv  (63 x 32)
    for (int f = t; f < MM * NB; f += 64) {
        int m = f >> 5, j = f & 31;
        double s = 0.0;
        for (int i = 0; i < NB; i++) s += Rl[m * NB + i] * aug[i * 64 + 32 + j];
        Qd[f] = s;
    }
    __syncthreads();

    // qt_bf [j 32][m 64], col 63 = 0
    {
        ush* qt = (ush*)(ws + OFF_QT_BF);
        for (int f = t; f < 32 * 64; f += 64) {
            int j = f >> 6, m = f & 63;
            qt[f] = f2bf(m < MM ? (float)Qd[m * NB + j] : 0.0f);
        }
    }
    // u[j] = sum_i Phi_inv[i][j]
    if (t < NB) {
        double s = 0.0;
        for (int i = 0; i < NB; i++) s += aug[i * 64 + 32 + t];
        ws[OFF_U + t] = (float)s;
    }
    // Phi_out [n][t] (32 x 16)
    if (t < TT) {
        double x = -1.0 + 2.0 * ((double)t_span[t] - t0) / (t1 - t0);
        double r0 = 1.0, r1 = x;
        ws[OFF_PHIOUT + 0 * TT + t] = 1.0f;
        ws[OFF_PHIOUT + 1 * TT + t] = (float)x;
        for (int n = 2; n < NB; n++) {
            double r2 = 2.0 * x * r1 - r0;
            ws[OFF_PHIOUT + n * TT + t] = (float)r2;
            r0 = r1; r1 = r2;
        }
    }
}

// ---------------------------------------------------------------------------
// Transpose fp32 (R x C) -> bf16 (C x R)
// ---------------------------------------------------------------------------
__global__ __launch_bounds__(256) void transpose_f32_bf16(
        const float* __restrict__ in, ush* __restrict__ out, int R, int C) {
    __shared__ float tile[32][33];
    const int t = threadIdx.x;
    const int tc = blockIdx.x, tr = blockIdx.y;
    const int c = tc * 32 + (t & 31);
    #pragma unroll
    for (int i = 0; i < 4; i++) {
        int rl = (t >> 5) + i * 8;
        tile[rl][t & 31] = in[(size_t)(tr * 32 + rl) * C + c];
    }
    __syncthreads();
    #pragma unroll
    for (int i = 0; i < 4; i++) {
        int orl = (t >> 5) + i * 8;
        int orow = tc * 32 + orl;
        int ocol = tr * 32 + (t & 31);
        out[(size_t)orow * R + ocol] = f2bf(tile[t & 31][orl]);
    }
}

// B_init [b][d][n] fp32 -> Bct [b][n][d] bf16
__global__ __launch_bounds__(256) void binit_kernel(
        const float* __restrict__ Bi, ush* __restrict__ Bct) {
    __shared__ float tile[32][33];
    const int t = threadIdx.x;
    const int b = blockIdx.y, d0 = blockIdx.x * 32;
    #pragma unroll
    for (int i = 0; i < 4; i++) {
        int f = i * 256 + t;
        int dd = f >> 5, n = f & 31;
        tile[dd][n] = Bi[((size_t)b * DD + d0 + dd) * NB + n];
    }
    __syncthreads();
    #pragma unroll
    for (int i = 0; i < 4; i++) {
        int f = i * 256 + t;
        int n = f >> 5, dd = f & 31;
        Bct[((size_t)b * NB + n) * DD + d0 + dd] = f2bf(tile[dd][n]);
    }
}

// ---------------------------------------------------------------------------
// Persistent per-b solver: 128 blocks x 1024 threads (16 waves = 4/SIMD,
// __launch_bounds__(1024,4) => 128-VGPR budget, no spills — R6's (1024,1)
// produced a 64-VGPR allocation and 750 MB of scratch spill traffic).
// Per iter: produce (each wave: 2 x 32-h chunks, G->Z->tanh->P into shared
// p_s; Z/tanh/P processed per 32-m half to halve accumulator liveness)
// -> barrier -> consume (each wave: 32-d slice, K=1024) -> epilogue
// -> barrier. 2 barriers/iter. No register prefetch: at 128 VGPR the
// compiler's own scheduling sufficed in R5.
// ---------------------------------------------------------------------------
__global__ __launch_bounds__(1024, 4) void solve_kernel(
        ush* __restrict__ Bct,            // [128][32][512] bf16, state
        const ush* __restrict__ W1t,      // [1024][512] bf16
        const ush* __restrict__ W2t,      // [512][1024] bf16
        const float* __restrict__ b1,     // [1024]
        const float* __restrict__ y_init, // [128][512]
        const float* __restrict__ ws,
        float* __restrict__ out)
{
    __shared__ __attribute__((aligned(16))) ush smem[LDS_TOT];
    ush* g_all = smem + LDS_G;
    ush* t_all = smem + LDS_T;
    ush* p_s   = smem + LDS_P;          // [32 j][stride 1048 ush]
    float* po_s = (float*)(smem + LDS_PO);

    const int tid  = threadIdx.x;
    const int w    = tid >> 6;          // 0..15
    const int lane = tid & 63;
    const int q    = lane >> 4;
    const int l15  = lane & 15;
    const int b    = blockIdx.x;
    const int dw   = w * 32;            // wave's d-slice for consume

    ush* gw = g_all + w * 1280;         // [32 h][40 n]
    ush* tw = t_all + w * 1280;         // [32 h][40 m-half]
    ush* bct = Bct + (size_t)b * (NB * DD);
    const ush* PF = (const ush*)(ws + OFF_PHIF_BF);
    const ush* QT = (const ush*)(ws + OFF_QT_BF);

    if (tid < 512) po_s[tid] = ws[OFF_PHIOUT + tid];

    // per-thread constants
    float yv[2];
    #pragma unroll
    for (int nt = 0; nt < 2; nt++)
        yv[nt] = y_init[(size_t)b * DD + dw + nt * 16 + l15];
    float4 uv[2], tt4[4];
    #pragma unroll
    for (int mt = 0; mt < 2; mt++) uv[mt] = *(const float4*)(ws + OFF_U + mt * 16 + q * 4);
    #pragma unroll
    for (int mt = 0; mt < 4; mt++) tt4[mt] = *(const float4*)(ws + OFF_TTRUE + mt * 16 + q * 4);
    __syncthreads();

    for (int it = 0; it < ITERS; it++) {
        // ================= produce: P[j][h] for this wave's 64 h =================
        for (int c = 0; c < 2; c++) {
            const int hb = w * 64 + c * 32;

            // ---- G = Bc^T W1 : M=32(n) N=32(h) K=512 ----
            f32x4 ag[2][2] = {};
            #pragma unroll 4
            for (int d0 = 0; d0 < DD; d0 += 32) {
                bf16x8 a0 = *(const bf16x8*)(bct + (size_t)l15 * DD + d0 + q * 8);
                bf16x8 a1 = *(const bf16x8*)(bct + (size_t)(16 + l15) * DD + d0 + q * 8);
                bf16x8 w0 = *(const bf16x8*)(W1t + (size_t)(hb + l15) * DD + d0 + q * 8);
                bf16x8 w1 = *(const bf16x8*)(W1t + (size_t)(hb + 16 + l15) * DD + d0 + q * 8);
                ag[0][0] = __builtin_amdgcn_mfma_f32_16x16x32_bf16(a0, w0, ag[0][0], 0, 0, 0);
                ag[0][1] = __builtin_amdgcn_mfma_f32_16x16x32_bf16(a0, w1, ag[0][1], 0, 0, 0);
                ag[1][0] = __builtin_amdgcn_mfma_f32_16x16x32_bf16(a1, w0, ag[1][0], 0, 0, 0);
                ag[1][1] = __builtin_amdgcn_mfma_f32_16x16x32_bf16(a1, w1, ag[1][1], 0, 0, 0);
            }
            // C-layout (row n=mt*16+q*4+r, col h=nt*16+l15) -> gw[h][n]
            #pragma unroll
            for (int mt = 0; mt < 2; mt++)
                #pragma unroll
                for (int nt = 0; nt < 2; nt++)
                    store4bf(gw + (nt * 16 + l15) * 40 + mt * 16 + q * 4,
                             ag[mt][nt][0], ag[mt][nt][1], ag[mt][nt][2], ag[mt][nt][3]);
            __builtin_amdgcn_s_waitcnt(0xc07f);  // lgkmcnt(0), wave-private RAW

            bf16x8 gb[2];
            #pragma unroll
            for (int nt = 0; nt < 2; nt++)
                gb[nt] = *(const bf16x8*)(gw + (nt * 16 + l15) * 40 + q * 8);

            // ---- per 32-m half: Z = Phi_f^T G, tanh, P += Q^T T ----
            float b1v[2] = { b1[hb + l15], b1[hb + 16 + l15] };
            f32x4 ap[2][2] = {};
            #pragma unroll
            for (int half = 0; half < 2; half++) {
                f32x4 az[2][2] = {};
                #pragma unroll
                for (int mt2 = 0; mt2 < 2; mt2++) {
                    int mt = half * 2 + mt2;
                    bf16x8 af = *(const bf16x8*)(PF + (mt * 16 + l15) * 32 + q * 8);
                    az[mt2][0] = __builtin_amdgcn_mfma_f32_16x16x32_bf16(af, gb[0], az[mt2][0], 0, 0, 0);
                    az[mt2][1] = __builtin_amdgcn_mfma_f32_16x16x32_bf16(af, gb[1], az[mt2][1], 0, 0, 0);
                }
                #pragma unroll
                for (int mt2 = 0; mt2 < 2; mt2++) {
                    int mt = half * 2 + mt2;
                    #pragma unroll
                    for (int nt = 0; nt < 2; nt++) {
                        float v0 = tanh_fast(az[mt2][nt][0] + tt4[mt].x * b1v[nt]);
                        float v1 = tanh_fast(az[mt2][nt][1] + tt4[mt].y * b1v[nt]);
                        float v2 = tanh_fast(az[mt2][nt][2] + tt4[mt].z * b1v[nt]);
                        float v3 = tanh_fast(az[mt2][nt][3] + tt4[mt].w * b1v[nt]);
                        store4bf(tw + (nt * 16 + l15) * 40 + mt2 * 16 + q * 4, v0, v1, v2, v3);
                    }
                }
                __builtin_amdgcn_s_waitcnt(0xc07f);
                bf16x8 tb[2];
                #pragma unroll
                for (int nt = 0; nt < 2; nt++)
                    tb[nt] = *(const bf16x8*)(tw + (nt * 16 + l15) * 40 + q * 8);
                #pragma unroll
                for (int jt = 0; jt < 2; jt++) {
                    bf16x8 aq = *(const bf16x8*)(QT + (jt * 16 + l15) * 64 + half * 32 + q * 8);
                    ap[jt][0] = __builtin_amdgcn_mfma_f32_16x16x32_bf16(aq, tb[0], ap[jt][0], 0, 0, 0);
                    ap[jt][1] = __builtin_amdgcn_mfma_f32_16x16x32_bf16(aq, tb[1], ap[jt][1], 0, 0, 0);
                }
            }
            // store P chunk: p_s[j][hb + hl]  (C-layout row j, col h)
            #pragma unroll
            for (int jt = 0; jt < 2; jt++)
                #pragma unroll
                for (int nt = 0; nt < 2; nt++)
                    #pragma unroll
                    for (int r = 0; r < 4; r++)
                        p_s[(jt * 16 + q * 4 + r) * 1048 + hb + nt * 16 + l15] =
                            f2bf(ap[jt][nt][r]);
        }
        __syncthreads();   // p_s complete

        // ================= consume: Bn[j][dw..dw+32] = P W2 + y u =================
        f32x4 ack[2][2] = {};
        #pragma unroll 4
        for (int s = 0; s < 32; s++) {
            bf16x8 wc0 = *(const bf16x8*)(W2t + (size_t)(dw + l15) * HH + s * 32 + q * 8);
            bf16x8 wc1 = *(const bf16x8*)(W2t + (size_t)(dw + 16 + l15) * HH + s * 32 + q * 8);
            bf16x8 pa0 = *(const bf16x8*)(p_s + l15 * 1048 + s * 32 + q * 8);
            bf16x8 pa1 = *(const bf16x8*)(p_s + (16 + l15) * 1048 + s * 32 + q * 8);
            ack[0][0] = __builtin_amdgcn_mfma_f32_16x16x32_bf16(pa0, wc0, ack[0][0], 0, 0, 0);
            ack[0][1] = __builtin_amdgcn_mfma_f32_16x16x32_bf16(pa0, wc1, ack[0][1], 0, 0, 0);
            ack[1][0] = __builtin_amdgcn_mfma_f32_16x16x32_bf16(pa1, wc0, ack[1][0], 0, 0, 0);
            ack[1][1] = __builtin_amdgcn_mfma_f32_16x16x32_bf16(pa1, wc1, ack[1][1], 0, 0, 0);
        }

        // ================= epilogue =================
        if (it < ITERS - 1) {
            #pragma unroll
            for (int mt = 0; mt < 2; mt++) {
                #pragma unroll
                for (int nt = 0; nt < 2; nt++) {
                    #pragma unroll
                    for (int r = 0; r < 4; r++) {
                        float uvr = (r == 0) ? uv[mt].x : (r == 1) ? uv[mt].y
                                  : (r == 2) ? uv[mt].z : uv[mt].w;
                        float val = ack[mt][nt][r] + yv[nt] * uvr;
                        bct[(size_t)(mt * 16 + q * 4 + r) * DD + dw + nt * 16 + l15] = f2bf(val);
                    }
                }
            }
            __syncthreads();   // bct visible + p_s consumed before next iter
        } else {
            // all waves done reading p_s before o0 overlays it
            __syncthreads();
            float* out1 = out + (size_t)TT * BB * DD;
            float* o0 = (float*)(smem + LDS_P);   // 16 t x 512 d fp32 (32 KB)
            #pragma unroll
            for (int nt = 0; nt < 2; nt++) {
                int d = dw + nt * 16 + l15;
                float po_acc[TT];
                #pragma unroll
                for (int t16 = 0; t16 < TT; t16++) po_acc[t16] = 0.0f;
                #pragma unroll
                for (int mt = 0; mt < 2; mt++) {
                    #pragma unroll
                    for (int r = 0; r < 4; r++) {
                        int j = mt * 16 + q * 4 + r;
                        float uvr = (r == 0) ? uv[mt].x : (r == 1) ? uv[mt].y
                                  : (r == 2) ? uv[mt].z : uv[mt].w;
                        float val = ack[mt][nt][r] + yv[nt] * uvr;
                        out1[(size_t)b * (DD * NB) + (size_t)d * NB + j] = val;
                        #pragma unroll
                        for (int t16 = 0; t16 < TT; t16++)
                            po_acc[t16] += val * po_s[j * TT + t16];
                    }
                }
                #pragma unroll
                for (int t16 = 0; t16 < TT; t16++) {
                    po_acc[t16] += __shfl_xor(po_acc[t16], 16);
                    po_acc[t16] += __shfl_xor(po_acc[t16], 32);
                }
                if (q == 0) {
                    #pragma unroll
                    for (int t16 = 0; t16 < TT; t16++)
                        o0[t16 * DD + d] = po_acc[t16];
                }
            }
            __syncthreads();
            #pragma unroll
            for (int i = 0; i < 8; i++) {
                int f = i * 1024 + tid;          // t16 = f>>9, d = f&511
                out[(size_t)(f >> 9) * (BB * DD) + (size_t)b * DD + (f & 511)] = o0[f];
            }
        }
    }
}

// ---------------------------------------------------------------------------
extern "C" void kernel_launch(void* const* d_in, const int* in_sizes, int n_in,
                              void* d_out, int out_size, void* d_ws, size_t ws_size,
                              hipStream_t stream) {
    const float* t_span = (const float*)d_in[0];
    const float* y_init = (const float*)d_in[1];
    const float* B_init = (const float*)d_in[2];
    const float* W1     = (const float*)d_in[3];
    const float* b1     = (const float*)d_in[4];
    const float* W2     = (const float*)d_in[5];
    float* ws  = (float*)d_ws;
    float* out = (float*)d_out;

    ush* Bct = (ush*)(ws + OFF_BCT);
    ush* W1t = (ush*)(ws + OFF_W1T);
    ush* W2t = (ush*)(ws + OFF_W2T);

    setup_kernel<<<1, 64, 0, stream>>>(t_span, ws);
    transpose_f32_bf16<<<dim3(HH / 32, DD / 32), 256, 0, stream>>>(W1, W1t, DD, HH);
    transpose_f32_bf16<<<dim3(DD / 32, HH / 32), 256, 0, stream>>>(W2, W2t, HH, DD);
    binit_kernel<<<dim3(DD / 32, BB), 256, 0, stream>>>(B_init, Bct);

    solve_kernel<<<dim3(BB), 1024, 0, stream>>>(Bct, W1t, W2t, b1, y_init, ws, out);
}